// Round 4
// baseline (240.621 us; speedup 1.0000x reference)
//
#include <hip/hip_runtime.h>
#include <stdint.h>

typedef __attribute__((ext_vector_type(8))) short short8;
typedef __attribute__((ext_vector_type(4))) float f32x4;

constexpr int Hc = 128, Wc = 128, HWc = Hc * Wc;
constexpr int Cin = 128, Cout = 128;
constexpr int OffC = 18, OffIn = 64;

__device__ __forceinline__ float bf2f(unsigned short u) {
    return __builtin_bit_cast(float, (unsigned)u << 16);
}
__device__ __forceinline__ unsigned short f2bf(float f) {
    unsigned u = __builtin_bit_cast(unsigned, f);
    return (unsigned short)((u + 0x7FFFu + ((u >> 16) & 1u)) >> 16);
}

// ---- 1x1 offset conv: off [B,64,HW] x w_off [18,64] + b_off -> offset [B,18,HW]
__global__ void k_offconv(const float* __restrict__ off, const float* __restrict__ w_off,
                          const float* __restrict__ b_off, float* __restrict__ offset) {
    __shared__ float wsm[OffC * OffIn];
    __shared__ float bsm[OffC];
    int tid = threadIdx.x;
    for (int i = tid; i < OffC * OffIn; i += 256) wsm[i] = w_off[i];
    if (tid < OffC) bsm[tid] = b_off[tid];
    __syncthreads();
    int g = blockIdx.x * 256 + tid;            // one pixel per thread
    int b = g >> 14, hw = g & (HWc - 1);
    const float* offb = off + b * OffIn * HWc + hw;
    float acc[OffC];
#pragma unroll
    for (int o = 0; o < OffC; ++o) acc[o] = bsm[o];
    for (int c = 0; c < OffIn; ++c) {
        float v = offb[c << 14];
#pragma unroll
        for (int o = 0; o < OffC; ++o) acc[o] += wsm[o * OffIn + c] * v;
    }
    float* outb = offset + b * OffC * HWc + hw;
#pragma unroll
    for (int o = 0; o < OffC; ++o) outb[o << 14] = acc[o];
}

// ---- x [B,C,H,W] fp32 -> x_t [B,H,W,C] bf16 (channels-last for coalesced gather)
__global__ void k_xpose(const float* __restrict__ x, unsigned short* __restrict__ xt) {
    __shared__ float tile[128][65];
    int blk = blockIdx.x;
    int b = blk >> 8;
    int hw0 = (blk & 255) << 6;
    const float* xb = x + b * Cin * HWc;
    int tid = threadIdx.x;
#pragma unroll
    for (int k = 0; k < 32; ++k) {
        int e = tid + k * 256;
        int c = e >> 6, p = e & 63;
        tile[c][p] = xb[(c << 14) + hw0 + p];
    }
    __syncthreads();
    unsigned short* xtb = xt + ((b << 14) + hw0) * Cin;
#pragma unroll
    for (int k = 0; k < 16; ++k) {
        int e = (tid + k * 256) * 2;
        int p = e >> 7, c = e & 127;
        unsigned lo = f2bf(tile[c][p]);
        unsigned hi = f2bf(tile[c + 1][p]);
        *(unsigned*)(xtb + e) = lo | (hi << 16);
    }
}

// ---- w_def [O,C,3,3] fp32 -> Wt [kk][O][C] bf16
__global__ void k_wprep(const float* __restrict__ wd, unsigned short* __restrict__ wt) {
    int i = blockIdx.x * 256 + threadIdx.x;
    int kk = i >> 14, o = (i >> 7) & 127, c = i & 127;
    wt[i] = f2bf(wd[((o << 7) + c) * 9 + kk]);
}

// ---- main: 512 blocks x 256 threads, 4 independent waves per block.
// One wave = 32 pixels (2 B-tiles) x 128 outputs (8 A-tiles). Zero LDS,
// zero barriers. Proven 16x16x32 fragment layouts (R0/R1).
__global__ __launch_bounds__(256)
void k_deform(const unsigned short* __restrict__ xt, const float* __restrict__ offset,
              const unsigned short* __restrict__ wt, float* __restrict__ out) {
    int tid = threadIdx.x;
    int lane = tid & 63, wave = tid >> 6;
    int bid = blockIdx.x;
    int swz = (bid & 7) * 64 + (bid >> 3);     // XCD-bijective (512 = 8*64)
    int b = swz >> 7;
    int hw0 = (swz & 127) << 7;                // 128-px block window
    int p0 = hw0 + (wave << 5) + (lane & 15);  // abs pixel, tile 0
    int p1 = p0 + 16;                          // abs pixel, tile 1
    int cg = lane >> 4;                        // k-group 0..3

    const unsigned short* xb = xt + ((size_t)b << 21);
    const float* offp = offset + (size_t)b * (OffC * HWc);

    int h0 = p0 >> 7, w0 = p0 & 127;
    int h1 = p1 >> 7, w1 = p1 & 127;

    f32x4 acc[8][2];
#pragma unroll
    for (int i = 0; i < 8; ++i)
#pragma unroll
        for (int j = 0; j < 2; ++j)
            acc[i][j] = (f32x4){0.f, 0.f, 0.f, 0.f};

    auto cparm = [&](int tap, float dy, float dx, int h, int w, float* cw, int* cb) {
        float ys = (float)(h - 1 + tap / 3) + dy;
        float xs = (float)(w - 1 + tap % 3) + dx;
        float y0f = floorf(ys), x0f = floorf(xs);
        float ly = ys - y0f, lx = xs - x0f;
        int y0 = (int)y0f, x0 = (int)x0f;
#pragma unroll
        for (int cr = 0; cr < 4; ++cr) {
            int yi = y0 + (cr >> 1), xi = x0 + (cr & 1);
            bool valid = (yi >= 0) && (yi < Hc) && (xi >= 0) && (xi < Wc);
            float wy = (cr >> 1) ? ly : 1.0f - ly;
            float wx = (cr & 1) ? lx : 1.0f - lx;
            int yc = yi < 0 ? 0 : (yi > Hc - 1 ? Hc - 1 : yi);
            int xc = xi < 0 ? 0 : (xi > Wc - 1 ? Wc - 1 : xi);
            cw[cr] = valid ? wy * wx : 0.0f;
            cb[cr] = ((yc << 7) + xc) << 7;    // element offset within batch slice
        }
    };

    // blend 4 corner short8's into one bf16 B-fragment
    auto blend = [&](const short8* r, const float* cw) -> short8 {
        short8 pk;
#pragma unroll
        for (int j = 0; j < 8; ++j) {
            float v = cw[0] * bf2f((unsigned short)r[0][j])
                    + cw[1] * bf2f((unsigned short)r[1][j])
                    + cw[2] * bf2f((unsigned short)r[2][j])
                    + cw[3] * bf2f((unsigned short)r[3][j]);
            pk[j] = (short)f2bf(v);
        }
        return pk;
    };

    float cw0[4], cw1[4]; int cb0[4], cb1[4];
    float dy0 = offp[p0], dx0 = offp[(1 << 14) + p0];
    float dy1 = offp[p1], dx1 = offp[(1 << 14) + p1];

    for (int t = 0; t < 9; ++t) {
        cparm(t, dy0, dx0, h0, w0, cw0, cb0);
        cparm(t, dy1, dx1, h1, w1, cw1, cb1);
        if (t < 8) {   // prefetch next tap's offsets (scalar, L1-hot)
            dy0 = offp[((2 * t + 2) << 14) + p0]; dx0 = offp[((2 * t + 3) << 14) + p0];
            dy1 = offp[((2 * t + 2) << 14) + p1]; dx1 = offp[((2 * t + 3) << 14) + p1];
        }
        const unsigned short* wtap = wt + (t << 14);
#pragma unroll
        for (int ks = 0; ks < 4; ++ks) {
            int kc = (ks << 5) + (cg << 3);
            short8 r0[4], r1[4];
#pragma unroll
            for (int cr = 0; cr < 4; ++cr) {
                r0[cr] = *(const short8*)(xb + cb0[cr] + kc);
                r1[cr] = *(const short8*)(xb + cb1[cr] + kc);
            }
            short8 A[8];
#pragma unroll
            for (int ot = 0; ot < 8; ++ot)
                A[ot] = *(const short8*)(wtap + ((ot << 4) + (lane & 15)) * 128 + kc);
            short8 bf0 = blend(r0, cw0);
            short8 bf1 = blend(r1, cw1);
#pragma unroll
            for (int ot = 0; ot < 8; ++ot) {
                acc[ot][0] = __builtin_amdgcn_mfma_f32_16x16x32_bf16(A[ot], bf0, acc[ot][0], 0, 0, 0);
                acc[ot][1] = __builtin_amdgcn_mfma_f32_16x16x32_bf16(A[ot], bf1, acc[ot][1], 0, 0, 0);
            }
        }
    }

    // epilogue: ReLU + fp32 store. D: col=lane&15 (pixel), row=(lane>>4)*4+j (o)
#pragma unroll
    for (int ot = 0; ot < 8; ++ot)
#pragma unroll
        for (int pt = 0; pt < 2; ++pt)
#pragma unroll
            for (int j = 0; j < 4; ++j) {
                int o = (ot << 4) + ((lane >> 4) << 2) + j;
                int px = hw0 + (wave << 5) + (pt << 4) + (lane & 15);
                float v = acc[ot][pt][j];
                out[(((size_t)(b << 7) + o) << 14) + px] = v > 0.f ? v : 0.f;
            }
}

extern "C" void kernel_launch(void* const* d_in, const int* in_sizes, int n_in,
                              void* d_out, int out_size, void* d_ws, size_t ws_size,
                              hipStream_t stream) {
    const float* x     = (const float*)d_in[0];
    const float* off   = (const float*)d_in[1];
    const float* w_off = (const float*)d_in[2];
    const float* b_off = (const float*)d_in[3];
    const float* w_def = (const float*)d_in[4];
    float* out = (float*)d_out;

    char* ws = (char*)d_ws;
    float* offset      = (float*)ws;                                  // 4,718,592 B
    unsigned short* xt = (unsigned short*)(ws + 4718592);             // 16,777,216 B
    unsigned short* wt = (unsigned short*)(ws + 4718592 + 16777216);  // 294,912 B

    hipLaunchKernelGGL(k_offconv, dim3(256),  dim3(256), 0, stream, off, w_off, b_off, offset);
    hipLaunchKernelGGL(k_xpose,   dim3(1024), dim3(256), 0, stream, x, xt);
    hipLaunchKernelGGL(k_wprep,   dim3(576),  dim3(256), 0, stream, w_def, wt);
    hipLaunchKernelGGL(k_deform,  dim3(512),  dim3(256), 0, stream, xt, offset, wt, out);
}